// Round 8
// baseline (284.821 us; speedup 1.0000x reference)
//
#include <hip/hip_runtime.h>
#include <hip/hip_bf16.h>

typedef __attribute__((ext_vector_type(8))) short short8;
typedef __attribute__((ext_vector_type(4))) short s16x4;
typedef __attribute__((ext_vector_type(4))) float f32x4;

typedef const __attribute__((address_space(1))) unsigned* gp1;
typedef __attribute__((address_space(3))) unsigned* lp3;

__device__ inline short f2bf(float f) {
    union { float f; unsigned u; } v; v.f = f;
    unsigned r = v.u + 0x7fffu + ((v.u >> 16) & 1u);
    return (short)(r >> 16);
}
__device__ inline short f2h(float f) {
    union { _Float16 h; short s; } u; u.h = (_Float16)f; return u.s;
}
__device__ inline float h2f(short s) {
    union { short s; _Float16 h; } u; u.s = s; return (float)u.h;
}

// ---------------------------------------------------------------------------
// P0: fp32 -> bf16 flat convert (x)
// ---------------------------------------------------------------------------
__global__ __launch_bounds__(256) void cvt_bf16(
    const float* __restrict__ src, short* __restrict__ dst, int n4)
{
    int i = blockIdx.x * 256 + threadIdx.x;
    if (i < n4) {
        float4 v = ((const float4*)src)[i];
        s16x4 o = { f2bf(v.x), f2bf(v.y), f2bf(v.z), f2bf(v.w) };
        ((s16x4*)dst)[i] = o;
    }
}

// ---------------------------------------------------------------------------
// P0b: fp32 -> fp16 flat convert (spd)
// ---------------------------------------------------------------------------
__global__ __launch_bounds__(256) void cvt_f16(
    const float* __restrict__ src, short* __restrict__ dst, int n4)
{
    int i = blockIdx.x * 256 + threadIdx.x;
    if (i < n4) {
        float4 v = ((const float4*)src)[i];
        s16x4 o = { f2h(v.x), f2h(v.y), f2h(v.z), f2h(v.w) };
        ((s16x4*)dst)[i] = o;
    }
}

// ---------------------------------------------------------------------------
// P1: W[K][N] fp32 -> W^T[N][K] bf16 (64x64 LDS tile transpose)
// ---------------------------------------------------------------------------
__global__ __launch_bounds__(256) void tr_w(
    const float* __restrict__ src, short* __restrict__ dst, int K, int N)
{
    __shared__ float t[64][65];
    const int k0 = blockIdx.x * 64, n0 = blockIdx.y * 64;
    const int r = threadIdx.x >> 4, c4 = (threadIdx.x & 15) * 4;
#pragma unroll
    for (int j = 0; j < 4; j++) {
        float4 v = *(const float4*)(src + (size_t)(k0 + r + 16 * j) * N + n0 + c4);
        t[r + 16 * j][c4 + 0] = v.x; t[r + 16 * j][c4 + 1] = v.y;
        t[r + 16 * j][c4 + 2] = v.z; t[r + 16 * j][c4 + 3] = v.w;
    }
    __syncthreads();
#pragma unroll
    for (int j = 0; j < 4; j++) {
        const int n = r + 16 * j;
        s16x4 o = { f2bf(t[c4 + 0][n]), f2bf(t[c4 + 1][n]),
                    f2bf(t[c4 + 2][n]), f2bf(t[c4 + 3][n]) };
        *(s16x4*)(dst + (size_t)(n0 + n) * K + k0 + c4) = o;
    }
}

// ---------------------------------------------------------------------------
// P2: v[bh][n][d] bf16 -> vt[bh][d][n] bf16 (64x64 tile transpose)
// ---------------------------------------------------------------------------
__global__ __launch_bounds__(256) void tv(
    const short* __restrict__ v, short* __restrict__ vt)
{
    __shared__ short t[64][72];   // 144B row stride: 16B-aligned b128 writes
    const int nt = blockIdx.x, bh = blockIdx.y;
    const int r = threadIdx.x >> 2, seg = (threadIdx.x & 3) * 16;
    const short* src = v + ((size_t)(bh * 1024 + nt * 64 + r)) * 64 + seg;
    *(short8*)&t[r][seg]     = *(const short8*)src;
    *(short8*)&t[r][seg + 8] = *(const short8*)(src + 8);
    __syncthreads();
    short8 a, c;
#pragma unroll
    for (int j = 0; j < 8; j++) a[j] = t[seg + j][r];
#pragma unroll
    for (int j = 0; j < 8; j++) c[j] = t[seg + 8 + j][r];
    short* dst = vt + ((size_t)(bh * 64 + r)) * 1024 + nt * 64 + seg;
    *(short8*)dst = a;
    *(short8*)(dst + 8) = c;
}

// ---------------------------------------------------------------------------
// K1: qkv = xb @ WqT^T  (M=8192, K=512, N=1536), 128x128 tile,
//     global_load_lds 16B staging; scatter epilogue to q/k/v (all row-major).
// ---------------------------------------------------------------------------
__global__ __launch_bounds__(256) void qkv_gemm(
    const short* __restrict__ A, const short* __restrict__ BT,
    short* __restrict__ q, short* __restrict__ k, short* __restrict__ vv)
{
    __shared__ short sA[128][32];   // NO padding: global_load_lds needs dense
    __shared__ short sB[128][32];

    const int tid  = threadIdx.x;
    const int wv   = tid >> 6, lane = tid & 63;
    const int quad = lane >> 4, l16 = lane & 15;
    const int wr = wv >> 1, wc = wv & 1;
    const int m0 = blockIdx.x * 128, n0 = blockIdx.y * 128;

    f32x4 acc[4][4];
#pragma unroll
    for (int i = 0; i < 4; i++)
#pragma unroll
        for (int j = 0; j < 4; j++) acc[i][j] = (f32x4){0.f, 0.f, 0.f, 0.f};

    const short* a_src = A  + (size_t)(m0 + wv * 32 + (lane >> 2)) * 512 + (lane & 3) * 8;
    const short* b_src = BT + (size_t)(n0 + wv * 32 + (lane >> 2)) * 512 + (lane & 3) * 8;
    char* a_dst = (char*)sA + wv * 2048;
    char* b_dst = (char*)sB + wv * 2048;

    for (int ks = 0; ks < 16; ks++) {
        __syncthreads();
        const short* ap = a_src + ks * 32;
        const short* bp = b_src + ks * 32;
        __builtin_amdgcn_global_load_lds((gp1)(ap),            (lp3)(a_dst),        16, 0, 0);
        __builtin_amdgcn_global_load_lds((gp1)(ap + 16 * 512), (lp3)(a_dst + 1024), 16, 0, 0);
        __builtin_amdgcn_global_load_lds((gp1)(bp),            (lp3)(b_dst),        16, 0, 0);
        __builtin_amdgcn_global_load_lds((gp1)(bp + 16 * 512), (lp3)(b_dst + 1024), 16, 0, 0);
        __syncthreads();

        short8 af[4], bf[4];
#pragma unroll
        for (int f = 0; f < 4; f++) {
            af[f] = *(const short8*)&sA[wr * 64 + f * 16 + l16][quad * 8];
            bf[f] = *(const short8*)&sB[wc * 64 + f * 16 + l16][quad * 8];
        }
#pragma unroll
        for (int fm = 0; fm < 4; fm++)
#pragma unroll
            for (int fn = 0; fn < 4; fn++)
                acc[fm][fn] = __builtin_amdgcn_mfma_f32_16x16x32_bf16(
                    af[fm], bf[fn], acc[fm][fn], 0, 0, 0);
    }

    const int sec = n0 >> 9;   // 0=q 1=k 2=v (uniform per block)
#pragma unroll
    for (int fn = 0; fn < 4; fn++) {
        const int gc = n0 + wc * 64 + fn * 16 + l16;
        const int cc = gc & 511;
        const int h = cc >> 6, d = cc & 63;
#pragma unroll
        for (int fm = 0; fm < 4; fm++)
#pragma unroll
            for (int i = 0; i < 4; i++) {
                const int gm = m0 + wr * 64 + fm * 16 + quad * 4 + i;
                const int b = gm >> 10, n = gm & 1023;
                const int bh = b * 8 + h;
                if (sec == 0)      q[((size_t)(bh * 1024 + n)) * 64 + d]  = f2bf(acc[fm][fn][i] * 0.125f);
                else if (sec == 1) k[((size_t)(bh * 1024 + n)) * 64 + d]  = f2bf(acc[fm][fn][i]);
                else               vv[((size_t)(bh * 1024 + n)) * 64 + d] = f2bf(acc[fm][fn][i]);
            }
    }
}

// ---------------------------------------------------------------------------
// K2: attention. Block = (b,h) x 16 q-rows; 4 waves x 256 cols.
// acc stripe in 64 regs/lane (fully unrolled). spd (pre-cvt fp16) staged via
// async global_load_lds into sP; NOTE global ptr must be PER-LANE (+lane*8
// shorts) — wave-uniform ptr replicates 16 bytes across the row (R7 bug).
// Passes read sv from LDS -> no svp VGPRs -> 4 blocks/CU. No max-sub
// (logits bounded ~25, exp safe in fp32). 4 barriers.
// ---------------------------------------------------------------------------
__global__ __launch_bounds__(256, 4) void attn_k(
    const short* __restrict__ q, const short* __restrict__ kk,
    const short* __restrict__ vt, const short* __restrict__ spd16,
    const float* __restrict__ hm, short* __restrict__ o)
{
    __shared__ short sP[16][1032];     // fp16 sv (staged), later bf16 P
    __shared__ float sred[3][4][16];   // 0=dn 1=pn 2=sum

    const int tid  = threadIdx.x;
    const int wv   = tid >> 6, lane = tid & 63;
    const int quad = lane >> 4, l16 = lane & 15;
    const int qt = blockIdx.x, bh = blockIdx.y;
    const int b = bh >> 3, h = bh & 7;
    const int q0 = qt * 16;

    // ---- async stage: spd16 stripe -> sP (fp16), 8 issues/wave ----
    {
        const short* base = spd16 + ((size_t)b * 1024 + q0) * 1024;
#pragma unroll
        for (int i2 = 0; i2 < 8; i2++) {
            const int row = wv * 4 + (i2 >> 1), half = i2 & 1;
            const short* gp = base + (size_t)row * 1024 + half * 512 + lane * 8;  // per-lane!
            __builtin_amdgcn_global_load_lds(
                (gp1)gp, (lp3)((char*)&sP[0][0] + row * 2064 + half * 1024), 16, 0, 0);
        }
    }

    // ---- QK^T: Q frags + 16 K-tiles, acc in regs ----
    const short* qb = q + ((size_t)bh * 1024 + q0 + l16) * 64;
    short8 aq0 = *(const short8*)(qb + quad * 8);
    short8 aq1 = *(const short8*)(qb + 32 + quad * 8);

    f32x4 acc[16];
#pragma unroll
    for (int t = 0; t < 16; t++) acc[t] = (f32x4){0.f, 0.f, 0.f, 0.f};

    const short* kbh = kk + (size_t)bh * 1024 * 64;
#pragma unroll
    for (int t = 0; t < 16; t++) {
        const short* kb = kbh + (size_t)(wv * 256 + t * 16 + l16) * 64;
        short8 b0 = *(const short8*)(kb + quad * 8);
        short8 b1 = *(const short8*)(kb + 32 + quad * 8);
        acc[t] = __builtin_amdgcn_mfma_f32_16x16x32_bf16(aq0, b0, acc[t], 0, 0, 0);
        acc[t] = __builtin_amdgcn_mfma_f32_16x16x32_bf16(aq1, b1, acc[t], 0, 0, 0);
    }
    __syncthreads();   // barrier 0: staging drained, sv readable

    // ---- pass 1: row norms of dots and dots*spd (sv from LDS fp16) ----
    float dn[4] = {0.f, 0.f, 0.f, 0.f}, pn[4] = {0.f, 0.f, 0.f, 0.f};
#pragma unroll
    for (int t = 0; t < 16; t++) {
        const int col = wv * 256 + t * 16 + l16;
#pragma unroll
        for (int i = 0; i < 4; i++) {
            float s  = acc[t][i];
            float sv = h2f(sP[quad * 4 + i][col]);
            float ps = s * sv;
            dn[i] += s * s;
            pn[i] += ps * ps;
        }
    }
#pragma unroll
    for (int m = 1; m < 16; m <<= 1)
#pragma unroll
        for (int i = 0; i < 4; i++) {
            dn[i] += __shfl_xor(dn[i], m, 64);
            pn[i] += __shfl_xor(pn[i], m, 64);
        }
    if (l16 == 0)
#pragma unroll
        for (int i = 0; i < 4; i++) {
            sred[0][wv][quad * 4 + i] = dn[i];
            sred[1][wv][quad * 4 + i] = pn[i];
        }
    __syncthreads();   // barrier 1
    float ratio[4];
#pragma unroll
    for (int i = 0; i < 4; i++) {
        const int row = quad * 4 + i;
        float d = sred[0][0][row] + sred[0][1][row] + sred[0][2][row] + sred[0][3][row];
        float p = sred[1][0][row] + sred[1][1][row] + sred[1][2][row] + sred[1][3][row];
        ratio[i] = sqrtf(d) / fmaxf(sqrtf(p), 1e-12f);
    }

    // ---- pass 2: logits + exp (no max-sub) + row sum ----
    float rs[4] = {0.f, 0.f, 0.f, 0.f};
#pragma unroll
    for (int t = 0; t < 16; t++) {
        const int col = wv * 256 + t * 16 + l16;
#pragma unroll
        for (int i = 0; i < 4; i++) {
            float sv = h2f(sP[quad * 4 + i][col]);
            float l  = acc[t][i] * fmaf(sv, ratio[i], 1.0f);
            float p  = __expf(l);
            acc[t][i] = p;
            rs[i] += p;
        }
    }
#pragma unroll
    for (int m = 1; m < 16; m <<= 1)
#pragma unroll
        for (int i = 0; i < 4; i++) rs[i] += __shfl_xor(rs[i], m, 64);
    if (l16 == 0)
#pragma unroll
        for (int i = 0; i < 4; i++) sred[2][wv][quad * 4 + i] = rs[i];
    __syncthreads();   // barrier 2: sums ready AND all sv reads done (sP reusable)
    const float hsum = hm[0] + hm[1] + hm[2] + hm[3] + hm[4] + hm[5] + hm[6] + hm[7];
    const float hscale = hm[h] * 8.0f / hsum;
    float rinv[4];
#pragma unroll
    for (int i = 0; i < 4; i++) {
        const int row = quad * 4 + i;
        float s = sred[2][0][row] + sred[2][1][row] + sred[2][2][row] + sred[2][3][row];
        rinv[i] = hscale / s;
    }

    // ---- P (scaled) -> sP bf16 (overwrites sv region) ----
#pragma unroll
    for (int t = 0; t < 16; t++) {
        const int col = wv * 256 + t * 16 + l16;
#pragma unroll
        for (int i = 0; i < 4; i++)
            sP[quad * 4 + i][col] = f2bf(acc[t][i] * rinv[i]);
    }
    __syncthreads();   // barrier 3

    // ---- O = P @ V : wave wv does v-dims [wv*16, wv*16+16) over K=1024 ----
    f32x4 oacc = (f32x4){0.f, 0.f, 0.f, 0.f};
    const short* vb = vt + ((size_t)bh * 64 + wv * 16 + l16) * 1024;
#pragma unroll
    for (int kkk = 0; kkk < 32; kkk++) {
        short8 pa = *(const short8*)&sP[l16][kkk * 32 + quad * 8];
        short8 vf = *(const short8*)(vb + kkk * 32 + quad * 8);
        oacc = __builtin_amdgcn_mfma_f32_16x16x32_bf16(pa, vf, oacc, 0, 0, 0);
    }
#pragma unroll
    for (int i = 0; i < 4; i++)
        o[((size_t)(b * 1024 + q0 + quad * 4 + i)) * 512 + h * 64 + wv * 16 + l16]
            = f2bf(oacc[i]);
}

// ---------------------------------------------------------------------------
// K3: out = O @ WoT^T + b_out  (M=8192, K=512, N=512), 128x128 tile, fp32 out
// ---------------------------------------------------------------------------
__global__ __launch_bounds__(256) void out_gemm(
    const short* __restrict__ A, const short* __restrict__ BT,
    const float* __restrict__ bias, float* __restrict__ out)
{
    __shared__ short sA[128][32];
    __shared__ short sB[128][32];

    const int tid  = threadIdx.x;
    const int wv   = tid >> 6, lane = tid & 63;
    const int quad = lane >> 4, l16 = lane & 15;
    const int wr = wv >> 1, wc = wv & 1;
    const int m0 = blockIdx.x * 128, n0 = blockIdx.y * 128;

    f32x4 acc[4][4];
#pragma unroll
    for (int i = 0; i < 4; i++)
#pragma unroll
        for (int j = 0; j < 4; j++) acc[i][j] = (f32x4){0.f, 0.f, 0.f, 0.f};

    const short* a_src = A  + (size_t)(m0 + wv * 32 + (lane >> 2)) * 512 + (lane & 3) * 8;
    const short* b_src = BT + (size_t)(n0 + wv * 32 + (lane >> 2)) * 512 + (lane & 3) * 8;
    char* a_dst = (char*)sA + wv * 2048;
    char* b_dst = (char*)sB + wv * 2048;

    for (int ks = 0; ks < 16; ks++) {
        __syncthreads();
        const short* ap = a_src + ks * 32;
        const short* bp = b_src + ks * 32;
        __builtin_amdgcn_global_load_lds((gp1)(ap),            (lp3)(a_dst),        16, 0, 0);
        __builtin_amdgcn_global_load_lds((gp1)(ap + 16 * 512), (lp3)(a_dst + 1024), 16, 0, 0);
        __builtin_amdgcn_global_load_lds((gp1)(bp),            (lp3)(b_dst),        16, 0, 0);
        __builtin_amdgcn_global_load_lds((gp1)(bp + 16 * 512), (lp3)(b_dst + 1024), 16, 0, 0);
        __syncthreads();

        short8 af[4], bf[4];
#pragma unroll
        for (int f = 0; f < 4; f++) {
            af[f] = *(const short8*)&sA[wr * 64 + f * 16 + l16][quad * 8];
            bf[f] = *(const short8*)&sB[wc * 64 + f * 16 + l16][quad * 8];
        }
#pragma unroll
        for (int fm = 0; fm < 4; fm++)
#pragma unroll
            for (int fn = 0; fn < 4; fn++)
                acc[fm][fn] = __builtin_amdgcn_mfma_f32_16x16x32_bf16(
                    af[fm], bf[fn], acc[fm][fn], 0, 0, 0);
    }

#pragma unroll
    for (int fn = 0; fn < 4; fn++) {
        const int gc = n0 + wc * 64 + fn * 16 + l16;
        const float bv = bias[gc];
#pragma unroll
        for (int fm = 0; fm < 4; fm++)
#pragma unroll
            for (int i = 0; i < 4; i++) {
                const int gm = m0 + wr * 64 + fm * 16 + quad * 4 + i;
                out[(size_t)gm * 512 + gc] = acc[fm][fn][i] + bv;
            }
    }
}

// ---------------------------------------------------------------------------
extern "C" void kernel_launch(void* const* d_in, const int* in_sizes, int n_in,
                              void* d_out, int out_size, void* d_ws, size_t ws_size,
                              hipStream_t stream) {
    const float* x    = (const float*)d_in[0];
    const float* spd  = (const float*)d_in[1];
    const float* hm   = (const float*)d_in[2];
    const float* Wqkv = (const float*)d_in[3];
    const float* Wout = (const float*)d_in[4];
    const float* bout = (const float*)d_in[5];
    float* out = (float*)d_out;

    char* ws = (char*)d_ws;
    short* qw   = (short*)(ws);                      // 8 MB  [bh][n][d] bf16 (pre-scaled)
    short* kw   = (short*)(ws + ((size_t)8  << 20)); // 8 MB  [bh][n][d] bf16
    short* vw   = (short*)(ws + ((size_t)16 << 20)); // 8 MB  [bh][n][d] bf16 row-major
    short* vtw  = (short*)(ws + ((size_t)24 << 20)); // 8 MB  [bh][d][n] bf16
    short* ow   = (short*)(ws + ((size_t)32 << 20)); // 8 MB  [b][n][h*64+d] bf16
    short* xb   = (short*)(ws + ((size_t)40 << 20)); // 8 MB  x bf16
    short* wqT  = (short*)(ws + ((size_t)48 << 20)); // 1.5MB Wqkv^T bf16
    short* woT  = (short*)(ws + ((size_t)50 << 20)); // 0.5MB Wout^T bf16
    short* spdh = (short*)(ws + ((size_t)52 << 20)); // 16.8MB spd fp16

    cvt_bf16<<<4096, 256, 0, stream>>>(x, xb, 8192 * 512 / 4);
    cvt_f16 <<<8192, 256, 0, stream>>>(spd, spdh, 8 * 1024 * 1024 / 4);
    tr_w    <<<dim3(8, 24), 256, 0, stream>>>(Wqkv, wqT, 512, 1536);
    tr_w    <<<dim3(8, 8),  256, 0, stream>>>(Wout, woT, 512, 512);

    qkv_gemm<<<dim3(64, 12), 256, 0, stream>>>(xb, wqT, qw, kw, vw);
    tv      <<<dim3(16, 64), 256, 0, stream>>>(vw, vtw);
    attn_k  <<<dim3(64, 64), 256, 0, stream>>>(qw, kw, vtw, spdh, hm, ow);
    out_gemm<<<dim3(64, 4),  256, 0, stream>>>(ow, woT, bout, out);
}